// Round 2
// baseline (10255.203 us; speedup 1.0000x reference)
//
#include <hip/hip_runtime.h>

// Conv2d 3x3, stride 1, pad 1, dilation 1.
// x: [32, 18, 256, 256] fp32, w: [64, 18, 3, 3] fp32, bias: [64] fp32
// out: [32, 64, 256, 256] fp32
//
// V3 changes vs V2 (4472 us — acc spilled to scratch, 19 GB HBM of spill traffic):
//   - __launch_bounds__(256, 4): VGPR budget 128 (acc[4][16]=64 + double x-window
//     ~36 fits; V2's ",6" forced <=85 regs -> catastrophic spill).
//     LDS stays chunked at 20.25 KB so LDS caps at 7 blocks/CU; VGPR caps at 4.
//   - Software pipeline: chunk loop fully unrolled, next ic's 18-element x-window
//     prefetched into a ping-pong register pair (statically indexed) while the
//     current ic's 144 FMAs run -> load latency hidden under compute.
// Kept from V1/V2: [k][oc] LDS weight layout (broadcast ds_read_b128), one-shot
// weight transpose pre-kernel for coalesced staging, 4 rows x 16 oc per thread,
// coalesced epilogue stores.

#define N_  32
#define IC_ 18
#define H_  256
#define W_  256
#define OC_ 64
#define KTOT (IC_ * 9)          // 162 taps per oc
#define ICC  9                  // input channels per staging chunk
#define KCH  (ICC * 9)          // 81 taps per chunk
#define CHW  (KCH * OC_)        // 5184 floats = 20.25 KB per chunk
#define HW_  (H_ * W_)

__global__ __launch_bounds__(256)
void transpose_w_kernel(const float* __restrict__ wgt, float* __restrict__ wT) {
    const int i = blockIdx.x * 256 + threadIdx.x;
    if (i < KTOT * OC_) {
        const int k  = i >> 6;          // tap index
        const int oc = i & 63;
        wT[i] = wgt[oc * KTOT + k];     // wT[k][oc]
    }
}

__device__ __forceinline__
void load_window(float (&xv)[6][3], const float* __restrict__ xc,
                 const int h0, const int w0, const int tx) {
    #pragma unroll
    for (int r = 0; r < 6; ++r) {
        const int gh = h0 - 1 + r;
        const bool rowOK = (unsigned)gh < (unsigned)H_;
        #pragma unroll
        for (int kw = 0; kw < 3; ++kw) {
            const int gw = w0 - 1 + tx + kw;
            const bool ok = rowOK && ((unsigned)gw < (unsigned)W_);
            xv[r][kw] = ok ? xc[gh * W_ + gw] : 0.0f;
        }
    }
}

__device__ __forceinline__
void compute9(float (&acc)[4][16], const float (&xv)[6][3],
              const float* __restrict__ wp0) {
    #pragma unroll
    for (int kh = 0; kh < 3; ++kh) {
        #pragma unroll
        for (int kw = 0; kw < 3; ++kw) {
            const float* wp = wp0 + (kh * 3 + kw) * OC_;  // wave-uniform addr
            float wr[16];
            #pragma unroll
            for (int o = 0; o < 16; ++o) wr[o] = wp[o];   // 4x ds_read_b128 broadcast
            #pragma unroll
            for (int ty = 0; ty < 4; ++ty) {
                const float xs = xv[ty + kh][kw];
                #pragma unroll
                for (int o = 0; o < 16; ++o)
                    acc[ty][o] = fmaf(xs, wr[o], acc[ty][o]);
            }
        }
    }
}

template<bool TRANS>
__global__ __launch_bounds__(256, 4)
void conv3x3_kernel(const float* __restrict__ x,
                    const float* __restrict__ wsrc,  // TRANS ? wT[k][oc] : wgt[oc][k]
                    const float* __restrict__ bias,
                    float* __restrict__ out) {
    __shared__ float wS[CHW];           // [k_local][oc] for current chunk

    const int tid    = threadIdx.x;
    const int tx     = tid & 63;        // output column within tile
    const int wv     = tid >> 6;        // wave id 0..3
    const int ocBase = wv * 16;
    const int w0     = blockIdx.x * 64; // tile col origin
    const int h0     = blockIdx.y * 4;  // tile row origin
    const int n      = blockIdx.z;

    float acc[4][16];
    #pragma unroll
    for (int o = 0; o < 16; ++o) {
        const float b = bias[ocBase + o];   // wave-uniform -> s_load
        #pragma unroll
        for (int ty = 0; ty < 4; ++ty) acc[ty][o] = b;
    }

    const float* xn = x + (size_t)n * IC_ * HW_;

    #pragma unroll 1
    for (int c = 0; c < IC_ / ICC; ++c) {
        __syncthreads();                 // LDS reuse guard (2 iters, cheap)
        if (TRANS) {
            const float4* src = (const float4*)(wsrc + c * CHW);
            float4*       dst = (float4*)wS;
            for (int i = tid; i < CHW / 4; i += 256) dst[i] = src[i];
        } else {
            for (int i = tid; i < CHW; i += 256) {
                const int k  = i >> 6;
                const int oc = i & 63;
                wS[i] = wsrc[oc * KTOT + c * KCH + k];
            }
        }
        __syncthreads();

        const float* xc0 = xn + c * ICC * HW_;

        // Ping-pong register windows; all indexing static under full unroll.
        float xa[6][3], xb[6][3];
        load_window(xa, xc0, h0, w0, tx);

        #pragma unroll
        for (int p = 0; p < ICC; ++p) {
            if (p + 1 < ICC) {
                if (p & 1) load_window(xa, xc0 + (p + 1) * HW_, h0, w0, tx);
                else       load_window(xb, xc0 + (p + 1) * HW_, h0, w0, tx);
            }
            if (p & 1) compute9(acc, xb, &wS[p * 9 * OC_ + ocBase]);
            else       compute9(acc, xa, &wS[p * 9 * OC_ + ocBase]);
        }
    }

    // Epilogue: coalesced stores (lanes = consecutive columns).
    #pragma unroll
    for (int o = 0; o < 16; ++o) {
        const int oc = ocBase + o;
        float* op = out + (((size_t)n * OC_ + oc) * H_ + h0) * (size_t)W_ + w0 + tx;
        #pragma unroll
        for (int ty = 0; ty < 4; ++ty)
            op[ty * W_] = acc[ty][o];
    }
}

extern "C" void kernel_launch(void* const* d_in, const int* in_sizes, int n_in,
                              void* d_out, int out_size, void* d_ws, size_t ws_size,
                              hipStream_t stream) {
    const float* x    = (const float*)d_in[0];
    const float* wgt  = (const float*)d_in[1];
    const float* bias = (const float*)d_in[2];
    float* out        = (float*)d_out;

    const size_t wT_bytes = (size_t)KTOT * OC_ * sizeof(float);  // 41472 B
    dim3 grid(W_ / 64, H_ / 4, N_);   // 4 x 64 x 32 = 8192 blocks
    dim3 block(256);

    if (d_ws != nullptr && ws_size >= wT_bytes) {
        float* wT = (float*)d_ws;
        hipLaunchKernelGGL(transpose_w_kernel,
                           dim3((KTOT * OC_ + 255) / 256), block, 0, stream,
                           wgt, wT);
        hipLaunchKernelGGL(conv3x3_kernel<true>, grid, block, 0, stream,
                           x, wT, bias, out);
    } else {
        hipLaunchKernelGGL(conv3x3_kernel<false>, grid, block, 0, stream,
                           x, wgt, bias, out);
    }
}

// Round 3
// 1767.599 us; speedup vs baseline: 5.8018x; 5.8018x over previous
//
#include <hip/hip_runtime.h>

// Conv2d 3x3, stride 1, pad 1, dilation 1.
// x: [32, 18, 256, 256] fp32, w: [64, 18, 3, 3] fp32, bias: [64] fp32
// out: [32, 64, 256, 256] fp32
//
// V4: weights moved from LDS broadcasts to SGPRs (s_load), LDS eliminated.
//   V1's bottleneck: 36 broadcast ds_read_b128 per ic per wave (16 oc x 9 taps)
//   at ~12 cyc on the CU-shared LDS pipe vs 144 FMA x 2 cyc per SIMD -> LDS
//   pipe oversubscribed ~6x, every tap serialized on lgkmcnt. VALUBusy 37%.
//   Fix: 4 oc per wave -> 36 wave-uniform weights per ic -> s_load to SGPRs
//   (v_fmac v, s, v). Zero LDS traffic; FMAs never wait on lgkm.
//   Occupancy lesson (V2/V3): allocator grants only (512/waves_per_eu)/2 arch
//   VGPRs on this toolchain; 64 acc/thread forces scratch spill above 3 w/EU.
//   Stay at __launch_bounds__(256,3), 84-VGPR budget, ~80 used, no spill.
//
// Layout: block = 4 waves, all waves share one 8-row x 64-col spatial tile
// (x windows L1-dedup'd across waves); wave wv covers oc quad
// (blockIdx-group*16 + wv*4). Lane = column; 8 rows x 4 oc = 32 acc.
// Column OOB masks hoisted out of the ic loop (2 cndmask/row); row bounds
// are scalar branches. x re-read 4x across oc-groups -> L2/L3-served.

#define N_  32
#define IC_ 18
#define H_  256
#define W_  256
#define OC_ 64
#define HW_ (H_ * W_)
#define KT_ (IC_ * 9)          // 162 taps per oc

__global__ __launch_bounds__(256, 3)
void conv3x3_kernel(const float* __restrict__ x,
                    const float* __restrict__ wgt,
                    const float* __restrict__ bias,
                    float* __restrict__ out) {
    const int tid = threadIdx.x;
    const int tx  = tid & 63;           // output column within tile
    const int wv  = tid >> 6;           // wave id 0..3 -> oc quad

    const int w0  = blockIdx.x * 64;    // tile col origin
    const int h0  = blockIdx.y * 8;     // tile row origin (8 rows/block)
    const int zz  = blockIdx.z;
    const int n   = zz >> 2;            // batch
    // Wave-uniform oc quad base; readfirstlane makes it manifestly scalar so
    // weight/bias loads compile to s_load (SGPR-resident weights).
    const int oc0 = __builtin_amdgcn_readfirstlane((zz & 3) * 16 + wv * 4);

    // Column indices: center always in-bounds; L/R clamped + masked.
    // Masks are ic- and row-invariant -> hoisted, 1 cndmask per masked load.
    const int  gwC = w0 + tx;
    const bool okL = (gwC >= 1);
    const bool okR = (gwC <= W_ - 2);
    const int  gwL = okL ? gwC - 1 : 0;
    const int  gwR = okR ? gwC + 1 : W_ - 1;

    float acc[8][4];
    #pragma unroll
    for (int o = 0; o < 4; ++o) {
        const float b = bias[oc0 + o];      // s_load (uniform)
        #pragma unroll
        for (int ty = 0; ty < 8; ++ty) acc[ty][o] = b;
    }

    const float* xn = x + (size_t)n * IC_ * HW_;

    #pragma unroll 1
    for (int ic = 0; ic < IC_; ++ic) {
        // 36 wave-uniform weights -> SGPRs (s_load through scalar cache).
        const float* wp = wgt + (size_t)oc0 * KT_ + ic * 9;
        float wr[4][9];
        #pragma unroll
        for (int o = 0; o < 4; ++o) {
            #pragma unroll
            for (int t = 0; t < 9; ++t)
                wr[o][t] = wp[o * KT_ + t];
        }

        const float* xc = xn + (size_t)ic * HW_;

        // x window: 10 rows x 3 cols in registers. Row checks scalar
        // (h0 is blockIdx-derived); only edge blocks take the zero path.
        float xw[10][3];
        #pragma unroll
        for (int r = 0; r < 10; ++r) {
            const int gh = h0 - 1 + r;
            if ((unsigned)gh < (unsigned)H_) {
                const float* row = xc + gh * W_;
                const float vL = row[gwL];
                const float vC = row[gwC];
                const float vR = row[gwR];
                xw[r][0] = okL ? vL : 0.0f;
                xw[r][1] = vC;
                xw[r][2] = okR ? vR : 0.0f;
            } else {
                xw[r][0] = 0.0f; xw[r][1] = 0.0f; xw[r][2] = 0.0f;
            }
        }

        // 288 FMAs: v_fmac_f32 v_acc, s_weight, v_x
        #pragma unroll
        for (int kh = 0; kh < 3; ++kh) {
            #pragma unroll
            for (int kw = 0; kw < 3; ++kw) {
                #pragma unroll
                for (int ty = 0; ty < 8; ++ty) {
                    const float xs = xw[ty + kh][kw];
                    #pragma unroll
                    for (int o = 0; o < 4; ++o)
                        acc[ty][o] = fmaf(xs, wr[o][kh * 3 + kw], acc[ty][o]);
                }
            }
        }
    }

    // Epilogue: coalesced stores (lanes = consecutive columns).
    #pragma unroll
    for (int o = 0; o < 4; ++o) {
        float* op = out + (((size_t)n * OC_ + (oc0 + o)) * H_ + h0) * (size_t)W_
                  + w0 + tx;
        #pragma unroll
        for (int ty = 0; ty < 8; ++ty)
            op[(size_t)ty * W_] = acc[ty][o];
    }
}

extern "C" void kernel_launch(void* const* d_in, const int* in_sizes, int n_in,
                              void* d_out, int out_size, void* d_ws, size_t ws_size,
                              hipStream_t stream) {
    const float* x    = (const float*)d_in[0];
    const float* wgt  = (const float*)d_in[1];
    const float* bias = (const float*)d_in[2];
    float* out        = (float*)d_out;

    // grid: 4 col-tiles x 32 row-tiles x (32 n * 4 oc-groups) = 16384 blocks
    dim3 grid(W_ / 64, H_ / 8, N_ * 4);
    dim3 block(256);
    hipLaunchKernelGGL(conv3x3_kernel, grid, block, 0, stream,
                       x, wgt, bias, out);
}